// Round 1
// baseline (6488.789 us; speedup 1.0000x reference)
//
#include <hip/hip_runtime.h>
#include <hip/hip_bf16.h>

// Problem constants
#define NB   128     // B*T = 16*8
#define CIN  128
#define CO   256
#define HIN  56
#define WIN  56
#define OH   28
#define OWW  28
#define P    784     // 28*28
#define HWIN 3136    // 56*56
#define PERT 200704  // CO*P (one timestep, one batch: C*H*W)

// ---------------------------------------------------------------------------
// K1: conv1 3x3 stride2 pad1 + BN1.  Grid (128, 128): x = co_tile*4 + sp_tile,
// y = n. Block 256. Each thread: 1 spatial position, 8 output channels.
// Weight addresses are wave-uniform -> scalar loads (SGPR operands to v_fma).
// ---------------------------------------------------------------------------
__global__ __launch_bounds__(256) void k_conv1(
    const float* __restrict__ x, const float* __restrict__ w1,
    const float* __restrict__ g, const float* __restrict__ be,
    const float* __restrict__ mu, const float* __restrict__ va,
    float* __restrict__ out)
{
    const int n   = blockIdx.y;
    const int co0 = (blockIdx.x >> 2) * 8;
    const int p   = (blockIdx.x & 3) * 256 + threadIdx.x;
    if (p >= P) return;
    const int oh = p / OWW, ow = p - oh * OWW;
    const int ih0 = 2 * oh - 1, iw0 = 2 * ow - 1;

    int  off[9];
    bool ok[9];
#pragma unroll
    for (int kh = 0; kh < 3; kh++)
#pragma unroll
        for (int kw = 0; kw < 3; kw++) {
            int ih = ih0 + kh, iw = iw0 + kw;
            bool o = ((unsigned)ih < (unsigned)HIN) && ((unsigned)iw < (unsigned)WIN);
            ok[kh * 3 + kw]  = o;
            off[kh * 3 + kw] = o ? (ih * WIN + iw) : 0;
        }

    const float* xn = x + (size_t)n * CIN * HWIN;
    float acc[8];
#pragma unroll
    for (int c = 0; c < 8; c++) acc[c] = 0.f;

    for (int ci = 0; ci < CIN; ci++) {
        const float* xc = xn + ci * HWIN;
        float vin[9];
#pragma unroll
        for (int k = 0; k < 9; k++) vin[k] = ok[k] ? xc[off[k]] : 0.f;
#pragma unroll
        for (int c = 0; c < 8; c++) {
            const float* wcc = w1 + (((size_t)(co0 + c) * CIN + ci) * 9);
#pragma unroll
            for (int k = 0; k < 9; k++)
                acc[c] = fmaf(vin[k], wcc[k], acc[c]);
        }
    }

#pragma unroll
    for (int c = 0; c < 8; c++) {
        int co = co0 + c;
        float inv = g[co] / sqrtf(va[co] + 1e-5f);
        float bb  = fmaf(-mu[co], inv, be[co]);
        out[((size_t)n * CO + co) * P + p] = fmaf(acc[c], inv, bb);
    }
}

// ---------------------------------------------------------------------------
// K2/K4: LIF over T=8. data layout [B=16, T=8, PERT]. Thread = one (b, c,h,w)
// lane; scans t. Exact reference recurrence: v = v + (x - v)*0.5; spike v>1;
// hard reset.
// ---------------------------------------------------------------------------
__global__ __launch_bounds__(256) void k_lif(const float* __restrict__ in,
                                             float* __restrict__ out)
{
    const int i = blockIdx.x * 256 + threadIdx.x;   // [0, 16*PERT)
    const int b = i / PERT;
    const int r = i - b * PERT;
    const float* pi = in  + (size_t)(b * 8) * PERT + r;
    float*       po = out + (size_t)(b * 8) * PERT + r;
    float v = 0.f;
#pragma unroll
    for (int t = 0; t < 8; t++) {
        float xt = pi[(size_t)t * PERT];
        v = v + (xt - v) * 0.5f;
        float s = (v > 1.0f) ? 1.f : 0.f;
        po[(size_t)t * PERT] = s;
        v = (v > 1.0f) ? 0.f : v;
    }
}

// ---------------------------------------------------------------------------
// K3: conv2 3x3 stride1 pad1 + BN2, fused with downsample 1x1 stride2 + BNd.
// Reads spikes s1 (d_out) and original x; writes pre-activation to ws.
// ---------------------------------------------------------------------------
__global__ __launch_bounds__(256) void k_conv2(
    const float* __restrict__ s1, const float* __restrict__ x,
    const float* __restrict__ w2, const float* __restrict__ wd,
    const float* __restrict__ g2, const float* __restrict__ b2,
    const float* __restrict__ m2, const float* __restrict__ v2,
    const float* __restrict__ gd, const float* __restrict__ bd,
    const float* __restrict__ md, const float* __restrict__ vd,
    float* __restrict__ out)
{
    const int n   = blockIdx.y;
    const int co0 = (blockIdx.x >> 2) * 8;
    const int p   = (blockIdx.x & 3) * 256 + threadIdx.x;
    if (p >= P) return;
    const int oh = p / OWW, ow = p - oh * OWW;
    const int ih0 = oh - 1, iw0 = ow - 1;

    int  off[9];
    bool ok[9];
#pragma unroll
    for (int kh = 0; kh < 3; kh++)
#pragma unroll
        for (int kw = 0; kw < 3; kw++) {
            int ih = ih0 + kh, iw = iw0 + kw;
            bool o = ((unsigned)ih < (unsigned)OH) && ((unsigned)iw < (unsigned)OWW);
            ok[kh * 3 + kw]  = o;
            off[kh * 3 + kw] = o ? (ih * OWW + iw) : 0;
        }

    const float* sn = s1 + (size_t)n * CO * P;
    float acc[8];
#pragma unroll
    for (int c = 0; c < 8; c++) acc[c] = 0.f;

    for (int ci = 0; ci < CO; ci++) {
        const float* sc = sn + ci * P;
        float vin[9];
#pragma unroll
        for (int k = 0; k < 9; k++) vin[k] = ok[k] ? sc[off[k]] : 0.f;
#pragma unroll
        for (int c = 0; c < 8; c++) {
            const float* wcc = w2 + (((size_t)(co0 + c) * CO + ci) * 9);
#pragma unroll
            for (int k = 0; k < 9; k++)
                acc[c] = fmaf(vin[k], wcc[k], acc[c]);
        }
    }

    // downsample shortcut: 1x1 stride 2 on x
    const float* xn = x + (size_t)n * CIN * HWIN;
    const int doff = (2 * oh) * WIN + 2 * ow;
    float accd[8];
#pragma unroll
    for (int c = 0; c < 8; c++) accd[c] = 0.f;
    for (int ci = 0; ci < CIN; ci++) {
        float v = xn[(size_t)ci * HWIN + doff];
#pragma unroll
        for (int c = 0; c < 8; c++)
            accd[c] = fmaf(v, wd[(size_t)(co0 + c) * CIN + ci], accd[c]);
    }

#pragma unroll
    for (int c = 0; c < 8; c++) {
        int co = co0 + c;
        float inv2 = g2[co] / sqrtf(v2[co] + 1e-5f);
        float bb2  = fmaf(-m2[co], inv2, b2[co]);
        float invd = gd[co] / sqrtf(vd[co] + 1e-5f);
        float bbd  = fmaf(-md[co], invd, bd[co]);
        float val  = fmaf(acc[c], inv2, bb2) + fmaf(accd[c], invd, bbd);
        out[((size_t)n * CO + co) * P + p] = val;
    }
}

extern "C" void kernel_launch(void* const* d_in, const int* in_sizes, int n_in,
                              void* d_out, int out_size, void* d_ws, size_t ws_size,
                              hipStream_t stream) {
    const float* x   = (const float*)d_in[0];
    const float* w1  = (const float*)d_in[1];
    const float* w2  = (const float*)d_in[2];
    const float* wd  = (const float*)d_in[3];
    const float* n1g = (const float*)d_in[4];
    const float* n1b = (const float*)d_in[5];
    const float* n1m = (const float*)d_in[6];
    const float* n1v = (const float*)d_in[7];
    const float* n2g = (const float*)d_in[8];
    const float* n2b = (const float*)d_in[9];
    const float* n2m = (const float*)d_in[10];
    const float* n2v = (const float*)d_in[11];
    const float* ndg = (const float*)d_in[12];
    const float* ndb = (const float*)d_in[13];
    const float* ndm = (const float*)d_in[14];
    const float* ndv = (const float*)d_in[15];

    float* out  = (float*)d_out;   // reused as conv1-out / spike buffer, then final
    float* pre2 = (float*)d_ws;    // 102.8 MB pre-activation buffer

    dim3 cgrid(128, 128);          // x = co_tile*4 + sp_tile, y = n

    k_conv1<<<cgrid, 256, 0, stream>>>(x, w1, n1g, n1b, n1m, n1v, out);
    k_lif<<<(16 * PERT) / 256, 256, 0, stream>>>(out, out);
    k_conv2<<<cgrid, 256, 0, stream>>>(out, x, w2, wd,
                                       n2g, n2b, n2m, n2v,
                                       ndg, ndb, ndm, ndv, pre2);
    k_lif<<<(16 * PERT) / 256, 256, 0, stream>>>(pre2, out);
}

// Round 2
// 3581.509 us; speedup vs baseline: 1.8117x; 1.8117x over previous
//
#include <hip/hip_runtime.h>
#include <hip/hip_bf16.h>

// Problem constants
#define CIN  128
#define CO   256
#define HIN  56
#define WIN  56
#define OH   28
#define OWW  28
#define P    784     // 28*28
#define HWIN 3136    // 56*56
#define PERT 200704  // CO*P

typedef __attribute__((ext_vector_type(8))) short bf16x8v;  // 8 bf16 in 4 VGPRs
typedef __attribute__((ext_vector_type(4))) float f32x4;

__device__ __forceinline__ f32x4 mfma16(bf16x8v a, bf16x8v b, f32x4 c) {
    return __builtin_amdgcn_mfma_f32_16x16x32_bf16(a, b, c, 0, 0, 0);
}

// ---------------------------------------------------------------------------
// K1: conv1 3x3 stride2 pad1 + BN1 (direct fp32 — known-good from R0).
// ---------------------------------------------------------------------------
__global__ __launch_bounds__(256) void k_conv1(
    const float* __restrict__ x, const float* __restrict__ w1,
    const float* __restrict__ g, const float* __restrict__ be,
    const float* __restrict__ mu, const float* __restrict__ va,
    float* __restrict__ out)
{
    const int n   = blockIdx.y;
    const int co0 = (blockIdx.x >> 2) * 8;
    const int p   = (blockIdx.x & 3) * 256 + threadIdx.x;
    if (p >= P) return;
    const int oh = p / OWW, ow = p - oh * OWW;
    const int ih0 = 2 * oh - 1, iw0 = 2 * ow - 1;

    int  off[9];
    bool ok[9];
#pragma unroll
    for (int kh = 0; kh < 3; kh++)
#pragma unroll
        for (int kw = 0; kw < 3; kw++) {
            int ih = ih0 + kh, iw = iw0 + kw;
            bool o = ((unsigned)ih < (unsigned)HIN) && ((unsigned)iw < (unsigned)WIN);
            ok[kh * 3 + kw]  = o;
            off[kh * 3 + kw] = o ? (ih * WIN + iw) : 0;
        }

    const float* xn = x + (size_t)n * CIN * HWIN;
    float acc[8];
#pragma unroll
    for (int c = 0; c < 8; c++) acc[c] = 0.f;

    for (int ci = 0; ci < CIN; ci++) {
        const float* xc = xn + ci * HWIN;
        float vin[9];
#pragma unroll
        for (int k = 0; k < 9; k++) vin[k] = ok[k] ? xc[off[k]] : 0.f;
#pragma unroll
        for (int c = 0; c < 8; c++) {
            const float* wcc = w1 + (((size_t)(co0 + c) * CIN + ci) * 9);
#pragma unroll
            for (int k = 0; k < 9; k++)
                acc[c] = fmaf(vin[k], wcc[k], acc[c]);
        }
    }

#pragma unroll
    for (int c = 0; c < 8; c++) {
        int co = co0 + c;
        float inv = g[co] / sqrtf(va[co] + 1e-5f);
        float bb  = fmaf(-mu[co], inv, be[co]);
        out[((size_t)n * CO + co) * P + p] = fmaf(acc[c], inv, bb);
    }
}

// ---------------------------------------------------------------------------
// Prep: BN fold scalars.  inv2/invd folded into weights; bias2 = bb2+bbd.
// ---------------------------------------------------------------------------
__global__ __launch_bounds__(256) void k_prep_bias(
    const float* __restrict__ g2, const float* __restrict__ b2,
    const float* __restrict__ m2, const float* __restrict__ v2,
    const float* __restrict__ gd, const float* __restrict__ bd,
    const float* __restrict__ md, const float* __restrict__ vd,
    float* __restrict__ inv2o, float* __restrict__ invdo,
    float* __restrict__ bias2o)
{
    int co = threadIdx.x;
    float inv2 = g2[co] / sqrtf(v2[co] + 1e-5f);
    float bb2  = fmaf(-m2[co], inv2, b2[co]);
    float invd = gd[co] / sqrtf(vd[co] + 1e-5f);
    float bbd  = fmaf(-md[co], invd, bd[co]);
    inv2o[co] = inv2; invdo[co] = invd; bias2o[co] = bb2 + bbd;
}

// w2 [co][ci][9] fp32 -> W2hi/lo [tap][co][ci] bf16 (scaled by inv2[co])
__global__ __launch_bounds__(256) void k_prep_w2(
    const float* __restrict__ w2, const float* __restrict__ inv2,
    __hip_bfloat16* __restrict__ hi, __hip_bfloat16* __restrict__ lo)
{
    int i = blockIdx.x * 256 + threadIdx.x;       // (tap, co, ci)
    if (i >= 9 * CO * CO) return;
    int tap = i / (CO * CO);
    int r   = i - tap * (CO * CO);
    int co  = r >> 8, ci = r & 255;
    float w = w2[((size_t)co * CO + ci) * 9 + tap] * inv2[co];
    __hip_bfloat16 h = __float2bfloat16(w);
    __hip_bfloat16 l = __float2bfloat16(w - __bfloat162float(h));
    hi[i] = h; lo[i] = l;
}

// wd [co][ci] fp32 -> Wdhi/lo [co][ci] bf16 (scaled by invd[co])
__global__ __launch_bounds__(256) void k_prep_wd(
    const float* __restrict__ wd, const float* __restrict__ invd,
    __hip_bfloat16* __restrict__ hi, __hip_bfloat16* __restrict__ lo)
{
    int i = blockIdx.x * 256 + threadIdx.x;       // (co, ci)
    if (i >= CO * CIN) return;
    int co = i >> 7;
    float w = wd[i] * invd[co];
    __hip_bfloat16 h = __float2bfloat16(w);
    __hip_bfloat16 l = __float2bfloat16(w - __bfloat162float(h));
    hi[i] = h; lo[i] = l;
}

// ---------------------------------------------------------------------------
// LIF1 + transpose: pre1 [16][8][256][784] fp32 -> spikes bf16 [128][784][256]
// Block: (b, co-tile 64, p-tile 16). Thread owns 4 (co,p) LIF states.
// ---------------------------------------------------------------------------
__global__ __launch_bounds__(256) void k_lif1t(
    const float* __restrict__ pre, unsigned short* __restrict__ st)
{
    __shared__ unsigned short T[16 * 68];     // [p 16][co 64 pad->68]
    const int b   = blockIdx.x;
    const int co0 = blockIdx.y * 64;
    const int p0  = blockIdx.z * 16;
    const int tid  = threadIdx.x;
    const int pcol = tid & 15;
    const int g    = tid >> 4;                // 0..15
    float v[4] = {0.f, 0.f, 0.f, 0.f};
    for (int t = 0; t < 8; t++) {
        const float* src = pre + (((size_t)(b * 8 + t)) * CO + co0) * P + p0;
        unsigned short s[4];
#pragma unroll
        for (int j = 0; j < 4; j++) {
            int co = g + 16 * j;
            float xv = src[(size_t)co * P + pcol];
            v[j] = v[j] + (xv - v[j]) * 0.5f;
            bool sp = v[j] > 1.0f;
            s[j] = sp ? 0x3F80 : 0;           // bf16(1.0) / bf16(0.0)
            if (sp) v[j] = 0.f;
        }
        __syncthreads();                      // protect prior iter's T reads
#pragma unroll
        for (int j = 0; j < 4; j++) T[pcol * 68 + g + 16 * j] = s[j];
        __syncthreads();
        // write out: thread -> row g, 4 consecutive co at pcol*4
        unsigned short* dst = st + ((size_t)(b * 8 + t) * P + p0 + g) * CO + co0 + pcol * 4;
        ushort4 o;
        o.x = T[g * 68 + pcol * 4 + 0];
        o.y = T[g * 68 + pcol * 4 + 1];
        o.z = T[g * 68 + pcol * 4 + 2];
        o.w = T[g * 68 + pcol * 4 + 3];
        *(ushort4*)dst = o;
    }
}

// ---------------------------------------------------------------------------
// conv2 3x3 s1 p1 (BN folded) + ds 1x1 s2 (BN folded) via bf16 MFMA, split
// weights (hi+lo) for fp32-exact products on binary spikes.
// Grid: x = n*7 + row_tile, y = co_blk(2). Block 256 = 4 waves.
// Wave: 2 co-frags (32 co) x 7 spatial frags (112 pos = 4 rows x 28 cols).
// ---------------------------------------------------------------------------
__global__ __launch_bounds__(256) void k_conv2_mfma(
    const unsigned short* __restrict__ spike_t,  // [128][784][256] bf16
    const float* __restrict__ x,                 // [128][128][3136]
    const unsigned short* __restrict__ w2hi,     // [9][256][256] bf16
    const unsigned short* __restrict__ w2lo,
    const unsigned short* __restrict__ wdhi,     // [256][128] bf16
    const unsigned short* __restrict__ wdlo,
    const float* __restrict__ bias2,             // [256]
    float* __restrict__ out)                     // [128][256][784]
{
    __shared__ unsigned short ST[6 * 30 * 32];   // 11520 B; reused for ds [112][32]

    const int n    = blockIdx.x / 7;
    const int rt   = blockIdx.x - n * 7;
    const int r0   = rt * 4;
    const int tid  = threadIdx.x;
    const int wave = tid >> 6;
    const int lane = tid & 63;
    const int l15  = lane & 15;
    const int quad = lane >> 4;
    const int co_w = blockIdx.y * 128 + wave * 32;

    int rr[7], cc[7];
#pragma unroll
    for (int f = 0; f < 7; f++) {
        int pos = f * 16 + l15;
        rr[f] = pos / 28;
        cc[f] = pos - rr[f] * 28;
    }

    f32x4 acc[2][7];
#pragma unroll
    for (int g = 0; g < 2; g++)
#pragma unroll
        for (int f = 0; f < 7; f++) acc[g][f] = (f32x4){0.f, 0.f, 0.f, 0.f};

    // ---- main conv2: 8 K-chunks of 32 ci over spikes ----
    const unsigned short* sp_n = spike_t + (size_t)n * P * CO;
    for (int ch = 0; ch < 8; ch++) {
        const int ci0 = ch * 32;
        __syncthreads();
        // stage [6 rows][30 cols][32 ci] bf16, zero-padded halo
        for (int i = tid; i < 720; i += 256) {        // 720 tasks x 16 B
            int part = i & 3, slot = i >> 2;
            int row = slot / 30, col = slot - row * 30;
            int irow = r0 - 1 + row, icol = col - 1;
            uint4 val = {0u, 0u, 0u, 0u};
            if ((unsigned)irow < 28u && (unsigned)icol < 28u)
                val = *(const uint4*)(sp_n + ((size_t)(irow * 28 + icol)) * CO + ci0 + part * 8);
            *(uint4*)(&ST[slot * 32 + part * 8]) = val;
        }
        __syncthreads();
        for (int tap = 0; tap < 9; tap++) {
            const int kh = tap / 3, kw = tap - kh * 3;
            const size_t wbase = ((size_t)tap * CO) * CO + (size_t)ci0 + quad * 8;
            bf16x8v a0h = *(const bf16x8v*)(w2hi + wbase + (size_t)(co_w + l15) * CO);
            bf16x8v a0l = *(const bf16x8v*)(w2lo + wbase + (size_t)(co_w + l15) * CO);
            bf16x8v a1h = *(const bf16x8v*)(w2hi + wbase + (size_t)(co_w + 16 + l15) * CO);
            bf16x8v a1l = *(const bf16x8v*)(w2lo + wbase + (size_t)(co_w + 16 + l15) * CO);
#pragma unroll
            for (int f = 0; f < 7; f++) {
                bf16x8v bfr = *(const bf16x8v*)(&ST[((rr[f] + kh) * 30 + cc[f] + kw) * 32 + quad * 8]);
                acc[0][f] = mfma16(a0h, bfr, acc[0][f]);
                acc[0][f] = mfma16(a0l, bfr, acc[0][f]);
                acc[1][f] = mfma16(a1h, bfr, acc[1][f]);
                acc[1][f] = mfma16(a1l, bfr, acc[1][f]);
            }
        }
    }

    // ---- ds shortcut: 4 K-chunks of 32 ci over x (stride-2 gather) ----
    const float* x_n = x + (size_t)n * CIN * HWIN;
    for (int ch = 0; ch < 4; ch++) {
        const int ci0 = ch * 32;
        __syncthreads();
        for (int i = tid; i < 3584; i += 256) {       // [ci 32][pos 112] tasks
            int ci = i / 112, pos = i - ci * 112;
            int r = pos / 28, c = pos - r * 28;
            float xv = x_n[(size_t)(ci0 + ci) * HWIN + (r0 + r) * 112 + c * 2];
            __hip_bfloat16 h = __float2bfloat16(xv);
            ST[pos * 32 + ci] = *(unsigned short*)&h;
        }
        __syncthreads();
        const size_t wb = (size_t)ci0 + quad * 8;
        bf16x8v a0h = *(const bf16x8v*)(wdhi + wb + (size_t)(co_w + l15) * CIN);
        bf16x8v a0l = *(const bf16x8v*)(wdlo + wb + (size_t)(co_w + l15) * CIN);
        bf16x8v a1h = *(const bf16x8v*)(wdhi + wb + (size_t)(co_w + 16 + l15) * CIN);
        bf16x8v a1l = *(const bf16x8v*)(wdlo + wb + (size_t)(co_w + 16 + l15) * CIN);
#pragma unroll
        for (int f = 0; f < 7; f++) {
            bf16x8v bfr = *(const bf16x8v*)(&ST[(f * 16 + l15) * 32 + quad * 8]);
            acc[0][f] = mfma16(a0h, bfr, acc[0][f]);
            acc[0][f] = mfma16(a0l, bfr, acc[0][f]);
            acc[1][f] = mfma16(a1h, bfr, acc[1][f]);
            acc[1][f] = mfma16(a1l, bfr, acc[1][f]);
        }
    }

    // ---- epilogue: D[reg] -> co = co_w + g*16 + quad*4 + reg, p = rt*112 + f*16 + l15
#pragma unroll
    for (int g = 0; g < 2; g++)
#pragma unroll
        for (int f = 0; f < 7; f++) {
            int pg = rt * 112 + f * 16 + l15;
#pragma unroll
            for (int reg = 0; reg < 4; reg++) {
                int co = co_w + g * 16 + quad * 4 + reg;
                out[((size_t)n * CO + co) * P + pg] = acc[g][f][reg] + bias2[co];
            }
        }
}

// ---------------------------------------------------------------------------
// LIF2: in-place over [B=16, T=8, PERT] (bias already added in conv2 epilogue)
// ---------------------------------------------------------------------------
__global__ __launch_bounds__(256) void k_lif(const float* __restrict__ in,
                                             float* __restrict__ out)
{
    const int i = blockIdx.x * 256 + threadIdx.x;
    const int b = i / PERT;
    const int r = i - b * PERT;
    const float* pi = in  + (size_t)(b * 8) * PERT + r;
    float*       po = out + (size_t)(b * 8) * PERT + r;
    float v = 0.f;
#pragma unroll
    for (int t = 0; t < 8; t++) {
        float xt = pi[(size_t)t * PERT];
        v = v + (xt - v) * 0.5f;
        float s = (v > 1.0f) ? 1.f : 0.f;
        po[(size_t)t * PERT] = s;
        v = (v > 1.0f) ? 0.f : v;
    }
}

extern "C" void kernel_launch(void* const* d_in, const int* in_sizes, int n_in,
                              void* d_out, int out_size, void* d_ws, size_t ws_size,
                              hipStream_t stream) {
    const float* x   = (const float*)d_in[0];
    const float* w1  = (const float*)d_in[1];
    const float* w2  = (const float*)d_in[2];
    const float* wd  = (const float*)d_in[3];
    const float* n1g = (const float*)d_in[4];
    const float* n1b = (const float*)d_in[5];
    const float* n1m = (const float*)d_in[6];
    const float* n1v = (const float*)d_in[7];
    const float* n2g = (const float*)d_in[8];
    const float* n2b = (const float*)d_in[9];
    const float* n2m = (const float*)d_in[10];
    const float* n2v = (const float*)d_in[11];
    const float* ndg = (const float*)d_in[12];
    const float* ndb = (const float*)d_in[13];
    const float* ndm = (const float*)d_in[14];
    const float* ndv = (const float*)d_in[15];

    float* out = (float*)d_out;

    // ws layout (16B-aligned)
    char* w = (char*)d_ws;
    unsigned short* spike_t = (unsigned short*)w;                    // 51,380,224 B
    unsigned short* w2hi    = (unsigned short*)(w + 51380224);       //  1,179,648 B
    unsigned short* w2lo    = (unsigned short*)(w + 52559872);       //  1,179,648 B
    unsigned short* wdhi    = (unsigned short*)(w + 53739520);       //     65,536 B
    unsigned short* wdlo    = (unsigned short*)(w + 53805056);       //     65,536 B
    float*          bias2   = (float*)(w + 53870592);                //      1,024 B
    float*          inv2    = (float*)(w + 53871616);
    float*          invd    = (float*)(w + 53872640);

    k_prep_bias<<<1, 256, 0, stream>>>(n2g, n2b, n2m, n2v, ndg, ndb, ndm, ndv,
                                       inv2, invd, bias2);
    k_prep_w2<<<(9 * CO * CO + 255) / 256, 256, 0, stream>>>(
        w2, inv2, (__hip_bfloat16*)w2hi, (__hip_bfloat16*)w2lo);
    k_prep_wd<<<(CO * CIN + 255) / 256, 256, 0, stream>>>(
        wd, invd, (__hip_bfloat16*)wdhi, (__hip_bfloat16*)wdlo);

    dim3 cgrid(128, 128);
    k_conv1<<<cgrid, 256, 0, stream>>>(x, w1, n1g, n1b, n1m, n1v, out);
    k_lif1t<<<dim3(16, 4, 49), 256, 0, stream>>>(out, spike_t);
    k_conv2_mfma<<<dim3(128 * 7, 2), 256, 0, stream>>>(
        spike_t, x, w2hi, w2lo, wdhi, wdlo, bias2, out);
    k_lif<<<(16 * PERT) / 256, 256, 0, stream>>>(out, out);
}

// Round 5
// 1003.290 us; speedup vs baseline: 6.4675x; 3.5698x over previous
//
#include <hip/hip_runtime.h>
#include <hip/hip_bf16.h>

// Problem constants
#define CIN  128
#define CO   256
#define HIN  56
#define WIN  56
#define OH   28
#define OWW  28
#define P    784     // 28*28
#define HWIN 3136    // 56*56
#define PERT 200704  // CO*P

typedef __attribute__((ext_vector_type(8))) short bf16x8v;  // 8 bf16 in 4 VGPRs
typedef __attribute__((ext_vector_type(4))) float f32x4;

__device__ __forceinline__ f32x4 mfma16(bf16x8v a, bf16x8v b, f32x4 c) {
    return __builtin_amdgcn_mfma_f32_16x16x32_bf16(a, b, c, 0, 0, 0);
}

// ---------------------------------------------------------------------------
// Prep: BN fold scalars for all three BNs.
// ---------------------------------------------------------------------------
__global__ __launch_bounds__(256) void k_prep_bias(
    const float* __restrict__ g1, const float* __restrict__ b1,
    const float* __restrict__ m1, const float* __restrict__ v1,
    const float* __restrict__ g2, const float* __restrict__ b2,
    const float* __restrict__ m2, const float* __restrict__ v2,
    const float* __restrict__ gd, const float* __restrict__ bd,
    const float* __restrict__ md, const float* __restrict__ vd,
    float* __restrict__ inv1o, float* __restrict__ bias1o,
    float* __restrict__ inv2o, float* __restrict__ invdo,
    float* __restrict__ bias2o)
{
    int co = threadIdx.x;
    float inv1 = g1[co] / sqrtf(v1[co] + 1e-5f);
    float inv2 = g2[co] / sqrtf(v2[co] + 1e-5f);
    float invd = gd[co] / sqrtf(vd[co] + 1e-5f);
    inv1o[co]  = inv1;
    bias1o[co] = fmaf(-m1[co], inv1, b1[co]);
    inv2o[co]  = inv2;
    invdo[co]  = invd;
    bias2o[co] = fmaf(-m2[co], inv2, b2[co]) + fmaf(-md[co], invd, bd[co]);
}

// w2 [co][ci][9] fp32 -> [tap][co][ci] bf16 hi/lo (scaled by inv2[co])
__global__ __launch_bounds__(256) void k_prep_w2(
    const float* __restrict__ w2, const float* __restrict__ inv2,
    __hip_bfloat16* __restrict__ hi, __hip_bfloat16* __restrict__ lo)
{
    int i = blockIdx.x * 256 + threadIdx.x;       // (tap, co, ci)
    if (i >= 9 * CO * CO) return;
    int tap = i / (CO * CO);
    int r   = i - tap * (CO * CO);
    int co  = r >> 8, ci = r & 255;
    float w = w2[((size_t)co * CO + ci) * 9 + tap] * inv2[co];
    __hip_bfloat16 h = __float2bfloat16(w);
    __hip_bfloat16 l = __float2bfloat16(w - __bfloat162float(h));
    hi[i] = h; lo[i] = l;
}

// w1 [co][ci][9] fp32 -> [tap][co][ci=128] bf16 hi/mid/lo (scaled by inv1[co])
// 3-term split represents the fp32 weight EXACTLY (24 mantissa bits covered).
__global__ __launch_bounds__(256) void k_prep_w1(
    const float* __restrict__ w1, const float* __restrict__ inv1,
    __hip_bfloat16* __restrict__ hi, __hip_bfloat16* __restrict__ mid,
    __hip_bfloat16* __restrict__ lo)
{
    int i = blockIdx.x * 256 + threadIdx.x;       // (tap, co, ci)
    if (i >= 9 * CO * CIN) return;
    int tap = i / (CO * CIN);
    int r   = i - tap * (CO * CIN);
    int co  = r >> 7, ci = r & 127;
    float w = w1[((size_t)co * CIN + ci) * 9 + tap] * inv1[co];
    __hip_bfloat16 h = __float2bfloat16(w);
    float r1 = w - __bfloat162float(h);
    __hip_bfloat16 m = __float2bfloat16(r1);
    float r2 = r1 - __bfloat162float(m);
    __hip_bfloat16 l = __float2bfloat16(r2);
    hi[i] = h; mid[i] = m; lo[i] = l;
}

// wd [co][ci] fp32 -> [co][ci] bf16 hi/lo (scaled by invd[co])
__global__ __launch_bounds__(256) void k_prep_wd(
    const float* __restrict__ wd, const float* __restrict__ invd,
    __hip_bfloat16* __restrict__ hi, __hip_bfloat16* __restrict__ lo)
{
    int i = blockIdx.x * 256 + threadIdx.x;       // (co, ci)
    if (i >= CO * CIN) return;
    int co = i >> 7;
    float w = wd[i] * invd[co];
    __hip_bfloat16 h = __float2bfloat16(w);
    __hip_bfloat16 l = __float2bfloat16(w - __bfloat162float(h));
    hi[i] = h; lo[i] = l;
}

// ---------------------------------------------------------------------------
// Pack x (binary fp32 [n][ci][3136]) -> bitmask xt_p [n][3136][4 words].
// ---------------------------------------------------------------------------
__global__ __launch_bounds__(256) void k_pack1(
    const float* __restrict__ x, unsigned int* __restrict__ xt_p)
{
    int i = blockIdx.x * 256 + threadIdx.x;       // ((n*4 + w)*3136 + pos)
    int pos = i % HWIN;
    int nw  = i / HWIN;
    int w   = nw & 3;
    int n   = nw >> 2;
    const float* xp = x + ((size_t)n * CIN + w * 32) * HWIN + pos;
    unsigned int word = 0;
#pragma unroll
    for (int ci = 0; ci < 32; ci++)
        if (xp[(size_t)ci * HWIN] != 0.f) word |= (1u << ci);
    xt_p[((size_t)n * HWIN + pos) * 4 + w] = word;
}

// ---------------------------------------------------------------------------
// conv1 3x3 stride2 pad1 (BN folded into weights) via bf16 MFMA on bit-packed
// spikes. Raw bit-words staged once in LDS; 8-bit -> bf16x8 unpack in regs.
// Weights as EXACT 3x bf16 split (hi+mid+lo): numerics = fp32-reorder only.
// Grid: x = n*7 + rt, y = co_blk(2). Block 256 = 4 waves.
// ---------------------------------------------------------------------------
__global__ __launch_bounds__(256) void k_conv1_mfma(
    const unsigned int* __restrict__ xt_p,       // [128][3136][4]
    const unsigned short* __restrict__ w1hi,     // [9][256][128] bf16
    const unsigned short* __restrict__ w1mid,
    const unsigned short* __restrict__ w1lo,
    const float* __restrict__ bias1,             // [256]
    float* __restrict__ out)                     // [128][256][784] pre-act
{
    __shared__ unsigned int XW[9 * 57 * 4];      // 8208 B

    const int n    = blockIdx.x / 7;
    const int rt   = blockIdx.x - n * 7;
    const int r0   = rt * 4;                     // first output row
    const int tid  = threadIdx.x;
    const int wave = tid >> 6;
    const int lane = tid & 63;
    const int l15  = lane & 15;
    const int quad = lane >> 4;
    const int co_w = blockIdx.y * 128 + wave * 32;

    const unsigned int* xp_n = xt_p + (size_t)n * HWIN * 4;

    // stage rows 0..8 (input rows 2*r0-1 .. 2*r0+7), cols iw=-1..55 at iw+1
    for (int i = tid; i < 513; i += 256) {
        int row = i / 57, c = i - row * 57;
        int irow = 2 * r0 - 1 + row;             // [-1, 55]
        int iw   = c - 1;                        // [-1, 55]
        uint4 val = {0u, 0u, 0u, 0u};
        if (irow >= 0 && iw >= 0)
            val = *(const uint4*)(xp_n + (size_t)(irow * WIN + iw) * 4);
        *(uint4*)(&XW[i * 4]) = val;
    }
    __syncthreads();

    int rr[7], cc[7];
#pragma unroll
    for (int f = 0; f < 7; f++) {
        int pos = f * 16 + l15;
        rr[f] = pos / 28;
        cc[f] = pos - rr[f] * 28;
    }

    f32x4 acc[2][7];
#pragma unroll
    for (int g = 0; g < 2; g++)
#pragma unroll
        for (int f = 0; f < 7; f++) acc[g][f] = (f32x4){0.f, 0.f, 0.f, 0.f};

    for (int ch = 0; ch < 4; ch++) {             // 4 chunks of 32 ci
        const int ci0 = ch * 32;
#pragma unroll
        for (int tap = 0; tap < 9; tap++) {
            const int kh = tap / 3, kw = tap - kh * 3;
            const size_t wbase = (size_t)tap * CO * CIN + ci0 + quad * 8;
            bf16x8v a0h = *(const bf16x8v*)(w1hi  + wbase + (size_t)(co_w + l15) * CIN);
            bf16x8v a0m = *(const bf16x8v*)(w1mid + wbase + (size_t)(co_w + l15) * CIN);
            bf16x8v a0l = *(const bf16x8v*)(w1lo  + wbase + (size_t)(co_w + l15) * CIN);
            bf16x8v a1h = *(const bf16x8v*)(w1hi  + wbase + (size_t)(co_w + 16 + l15) * CIN);
            bf16x8v a1m = *(const bf16x8v*)(w1mid + wbase + (size_t)(co_w + 16 + l15) * CIN);
            bf16x8v a1l = *(const bf16x8v*)(w1lo  + wbase + (size_t)(co_w + 16 + l15) * CIN);
#pragma unroll
            for (int f = 0; f < 7; f++) {
                // input row = 2*(r0+rr)-1+kh -> LDS row 2*rr+kh
                // input col = 2*cc-1+kw      -> LDS col (iw+1) = 2*cc+kw
                unsigned int word = XW[((2 * rr[f] + kh) * 57 + 2 * cc[f] + kw) * 4 + ch];
                unsigned int byt  = (word >> (quad * 8)) & 0xffu;
                uint4 u;
                u.x = ((byt & 1u)   ? 0x3F80u : 0u) | ((byt & 2u)   ? 0x3F800000u : 0u);
                u.y = ((byt & 4u)   ? 0x3F80u : 0u) | ((byt & 8u)   ? 0x3F800000u : 0u);
                u.z = ((byt & 16u)  ? 0x3F80u : 0u) | ((byt & 32u)  ? 0x3F800000u : 0u);
                u.w = ((byt & 64u)  ? 0x3F80u : 0u) | ((byt & 128u) ? 0x3F800000u : 0u);
                union { uint4 q; bf16x8v v; } cv;
                cv.q = u;
                acc[0][f] = mfma16(a0h, cv.v, acc[0][f]);
                acc[0][f] = mfma16(a0m, cv.v, acc[0][f]);
                acc[0][f] = mfma16(a0l, cv.v, acc[0][f]);
                acc[1][f] = mfma16(a1h, cv.v, acc[1][f]);
                acc[1][f] = mfma16(a1m, cv.v, acc[1][f]);
                acc[1][f] = mfma16(a1l, cv.v, acc[1][f]);
            }
        }
    }

    // epilogue: co = co_w + g*16 + quad*4 + reg, p = rt*112 + f*16 + l15
#pragma unroll
    for (int g = 0; g < 2; g++)
#pragma unroll
        for (int f = 0; f < 7; f++) {
            int pg = rt * 112 + f * 16 + l15;
#pragma unroll
            for (int reg = 0; reg < 4; reg++) {
                int co = co_w + g * 16 + quad * 4 + reg;
                out[((size_t)n * CO + co) * P + pg] = acc[g][f][reg] + bias1[co];
            }
        }
}

// ---------------------------------------------------------------------------
// LIF1 + transpose: pre1 [16][8][256][784] fp32 -> spikes bf16 [128][784][256]
// ---------------------------------------------------------------------------
__global__ __launch_bounds__(256) void k_lif1t(
    const float* __restrict__ pre, unsigned short* __restrict__ st)
{
    __shared__ unsigned short T[16 * 68];
    const int b   = blockIdx.x;
    const int co0 = blockIdx.y * 64;
    const int p0  = blockIdx.z * 16;
    const int tid  = threadIdx.x;
    const int pcol = tid & 15;
    const int g    = tid >> 4;
    float v[4] = {0.f, 0.f, 0.f, 0.f};
    for (int t = 0; t < 8; t++) {
        const float* src = pre + (((size_t)(b * 8 + t)) * CO + co0) * P + p0;
        unsigned short s[4];
#pragma unroll
        for (int j = 0; j < 4; j++) {
            int co = g + 16 * j;
            float xv = src[(size_t)co * P + pcol];
            v[j] = v[j] + (xv - v[j]) * 0.5f;
            bool sp = v[j] > 1.0f;
            s[j] = sp ? 0x3F80 : 0;
            if (sp) v[j] = 0.f;
        }
        __syncthreads();
#pragma unroll
        for (int j = 0; j < 4; j++) T[pcol * 68 + g + 16 * j] = s[j];
        __syncthreads();
        unsigned short* dst = st + ((size_t)(b * 8 + t) * P + p0 + g) * CO + co0 + pcol * 4;
        ushort4 o;
        o.x = T[g * 68 + pcol * 4 + 0];
        o.y = T[g * 68 + pcol * 4 + 1];
        o.z = T[g * 68 + pcol * 4 + 2];
        o.w = T[g * 68 + pcol * 4 + 3];
        *(ushort4*)dst = o;
    }
}

// ---------------------------------------------------------------------------
// conv2 3x3 s1 p1 (BN folded) + ds 1x1 s2 (BN folded) via bf16 MFMA.
// (proven in R2 — unchanged)
// ---------------------------------------------------------------------------
__global__ __launch_bounds__(256) void k_conv2_mfma(
    const unsigned short* __restrict__ spike_t,  // [128][784][256] bf16
    const float* __restrict__ x,                 // [128][128][3136]
    const unsigned short* __restrict__ w2hi,     // [9][256][256] bf16
    const unsigned short* __restrict__ w2lo,
    const unsigned short* __restrict__ wdhi,     // [256][128] bf16
    const unsigned short* __restrict__ wdlo,
    const float* __restrict__ bias2,             // [256]
    float* __restrict__ out)                     // [128][256][784]
{
    __shared__ unsigned short ST[6 * 30 * 32];

    const int n    = blockIdx.x / 7;
    const int rt   = blockIdx.x - n * 7;
    const int r0   = rt * 4;
    const int tid  = threadIdx.x;
    const int wave = tid >> 6;
    const int lane = tid & 63;
    const int l15  = lane & 15;
    const int quad = lane >> 4;
    const int co_w = blockIdx.y * 128 + wave * 32;

    int rr[7], cc[7];
#pragma unroll
    for (int f = 0; f < 7; f++) {
        int pos = f * 16 + l15;
        rr[f] = pos / 28;
        cc[f] = pos - rr[f] * 28;
    }

    f32x4 acc[2][7];
#pragma unroll
    for (int g = 0; g < 2; g++)
#pragma unroll
        for (int f = 0; f < 7; f++) acc[g][f] = (f32x4){0.f, 0.f, 0.f, 0.f};

    const unsigned short* sp_n = spike_t + (size_t)n * P * CO;
    for (int ch = 0; ch < 8; ch++) {
        const int ci0 = ch * 32;
        __syncthreads();
        for (int i = tid; i < 720; i += 256) {
            int part = i & 3, slot = i >> 2;
            int row = slot / 30, col = slot - row * 30;
            int irow = r0 - 1 + row, icol = col - 1;
            uint4 val = {0u, 0u, 0u, 0u};
            if ((unsigned)irow < 28u && (unsigned)icol < 28u)
                val = *(const uint4*)(sp_n + ((size_t)(irow * 28 + icol)) * CO + ci0 + part * 8);
            *(uint4*)(&ST[slot * 32 + part * 8]) = val;
        }
        __syncthreads();
        for (int tap = 0; tap < 9; tap++) {
            const int kh = tap / 3, kw = tap - kh * 3;
            const size_t wbase = ((size_t)tap * CO) * CO + (size_t)ci0 + quad * 8;
            bf16x8v a0h = *(const bf16x8v*)(w2hi + wbase + (size_t)(co_w + l15) * CO);
            bf16x8v a0l = *(const bf16x8v*)(w2lo + wbase + (size_t)(co_w + l15) * CO);
            bf16x8v a1h = *(const bf16x8v*)(w2hi + wbase + (size_t)(co_w + 16 + l15) * CO);
            bf16x8v a1l = *(const bf16x8v*)(w2lo + wbase + (size_t)(co_w + 16 + l15) * CO);
#pragma unroll
            for (int f = 0; f < 7; f++) {
                bf16x8v bfr = *(const bf16x8v*)(&ST[((rr[f] + kh) * 30 + cc[f] + kw) * 32 + quad * 8]);
                acc[0][f] = mfma16(a0h, bfr, acc[0][f]);
                acc[0][f] = mfma16(a0l, bfr, acc[0][f]);
                acc[1][f] = mfma16(a1h, bfr, acc[1][f]);
                acc[1][f] = mfma16(a1l, bfr, acc[1][f]);
            }
        }
    }

    const float* x_n = x + (size_t)n * CIN * HWIN;
    for (int ch = 0; ch < 4; ch++) {
        const int ci0 = ch * 32;
        __syncthreads();
        for (int i = tid; i < 3584; i += 256) {
            int ci = i / 112, pos = i - ci * 112;
            int r = pos / 28, c = pos - r * 28;
            float xv = x_n[(size_t)(ci0 + ci) * HWIN + (r0 + r) * 112 + c * 2];
            __hip_bfloat16 h = __float2bfloat16(xv);
            ST[pos * 32 + ci] = *(unsigned short*)&h;
        }
        __syncthreads();
        const size_t wb = (size_t)ci0 + quad * 8;
        bf16x8v a0h = *(const bf16x8v*)(wdhi + wb + (size_t)(co_w + l15) * CIN);
        bf16x8v a0l = *(const bf16x8v*)(wdlo + wb + (size_t)(co_w + l15) * CIN);
        bf16x8v a1h = *(const bf16x8v*)(wdhi + wb + (size_t)(co_w + 16 + l15) * CIN);
        bf16x8v a1l = *(const bf16x8v*)(wdlo + wb + (size_t)(co_w + 16 + l15) * CIN);
#pragma unroll
        for (int f = 0; f < 7; f++) {
            bf16x8v bfr = *(const bf16x8v*)(&ST[(f * 16 + l15) * 32 + quad * 8]);
            acc[0][f] = mfma16(a0h, bfr, acc[0][f]);
            acc[0][f] = mfma16(a0l, bfr, acc[0][f]);
            acc[1][f] = mfma16(a1h, bfr, acc[1][f]);
            acc[1][f] = mfma16(a1l, bfr, acc[1][f]);
        }
    }

#pragma unroll
    for (int g = 0; g < 2; g++)
#pragma unroll
        for (int f = 0; f < 7; f++) {
            int pg = rt * 112 + f * 16 + l15;
#pragma unroll
            for (int reg = 0; reg < 4; reg++) {
                int co = co_w + g * 16 + quad * 4 + reg;
                out[((size_t)n * CO + co) * P + pg] = acc[g][f][reg] + bias2[co];
            }
        }
}

// ---------------------------------------------------------------------------
// LIF2: in-place over [B=16, T=8, PERT]
// ---------------------------------------------------------------------------
__global__ __launch_bounds__(256) void k_lif(const float* __restrict__ in,
                                             float* __restrict__ out)
{
    const int i = blockIdx.x * 256 + threadIdx.x;
    const int b = i / PERT;
    const int r = i - b * PERT;
    const float* pi = in  + (size_t)(b * 8) * PERT + r;
    float*       po = out + (size_t)(b * 8) * PERT + r;
    float v = 0.f;
#pragma unroll
    for (int t = 0; t < 8; t++) {
        float xt = pi[(size_t)t * PERT];
        v = v + (xt - v) * 0.5f;
        float s = (v > 1.0f) ? 1.f : 0.f;
        po[(size_t)t * PERT] = s;
        v = (v > 1.0f) ? 0.f : v;
    }
}

extern "C" void kernel_launch(void* const* d_in, const int* in_sizes, int n_in,
                              void* d_out, int out_size, void* d_ws, size_t ws_size,
                              hipStream_t stream) {
    const float* x   = (const float*)d_in[0];
    const float* w1  = (const float*)d_in[1];
    const float* w2  = (const float*)d_in[2];
    const float* wd  = (const float*)d_in[3];
    const float* n1g = (const float*)d_in[4];
    const float* n1b = (const float*)d_in[5];
    const float* n1m = (const float*)d_in[6];
    const float* n1v = (const float*)d_in[7];
    const float* n2g = (const float*)d_in[8];
    const float* n2b = (const float*)d_in[9];
    const float* n2m = (const float*)d_in[10];
    const float* n2v = (const float*)d_in[11];
    const float* ndg = (const float*)d_in[12];
    const float* ndb = (const float*)d_in[13];
    const float* ndm = (const float*)d_in[14];
    const float* ndv = (const float*)d_in[15];

    float* out = (float*)d_out;   // pre1 -> (lif1t) -> pre2 -> final spikes

    // ws layout (1KB-aligned); total ~62.1 MB
    char* w = (char*)d_ws;
    unsigned short* spike_t = (unsigned short*)w;                    // 51,380,224
    unsigned short* w2hi    = (unsigned short*)(w + 51380224);       //  1,179,648
    unsigned short* w2lo    = (unsigned short*)(w + 52559872);       //  1,179,648
    unsigned short* w1hi    = (unsigned short*)(w + 53739520);       //    589,824
    unsigned short* w1mid   = (unsigned short*)(w + 54329344);       //    589,824
    unsigned short* w1lo    = (unsigned short*)(w + 54919168);       //    589,824
    unsigned short* wdhi    = (unsigned short*)(w + 55508992);       //     65,536
    unsigned short* wdlo    = (unsigned short*)(w + 55574528);       //     65,536
    float*          bias2   = (float*)(w + 55640064);
    float*          bias1   = (float*)(w + 55641088);
    float*          inv1    = (float*)(w + 55642112);
    float*          inv2    = (float*)(w + 55643136);
    float*          invd    = (float*)(w + 55644160);
    unsigned int*   xt_p    = (unsigned int*)(w + 55645184);         //  6,422,528

    k_prep_bias<<<1, 256, 0, stream>>>(n1g, n1b, n1m, n1v,
                                       n2g, n2b, n2m, n2v,
                                       ndg, ndb, ndm, ndv,
                                       inv1, bias1, inv2, invd, bias2);
    k_prep_w2<<<(9 * CO * CO + 255) / 256, 256, 0, stream>>>(
        w2, inv2, (__hip_bfloat16*)w2hi, (__hip_bfloat16*)w2lo);
    k_prep_w1<<<(9 * CO * CIN + 255) / 256, 256, 0, stream>>>(
        w1, inv1, (__hip_bfloat16*)w1hi, (__hip_bfloat16*)w1mid, (__hip_bfloat16*)w1lo);
    k_prep_wd<<<(CO * CIN + 255) / 256, 256, 0, stream>>>(
        wd, invd, (__hip_bfloat16*)wdhi, (__hip_bfloat16*)wdlo);

    k_pack1<<<(128 * 4 * HWIN) / 256, 256, 0, stream>>>(x, xt_p);
    k_conv1_mfma<<<dim3(128 * 7, 2), 256, 0, stream>>>(
        xt_p, w1hi, w1mid, w1lo, bias1, out);
    k_lif1t<<<dim3(16, 4, 49), 256, 0, stream>>>(out, spike_t);
    k_conv2_mfma<<<dim3(128 * 7, 2), 256, 0, stream>>>(
        spike_t, x, w2hi, w2lo, wdhi, wdlo, bias2, out);
    k_lif<<<(16 * PERT) / 256, 256, 0, stream>>>(out, out);
}